// Round 9
// baseline (159.815 us; speedup 1.0000x reference)
//
#include <hip/hip_runtime.h>
#include <hip/hip_bf16.h>

// LightningAttention MI355X — round 9.
// R8 + (1) x staged as bf16-hi only (A=x_hi, W stays hi+lo split): 96 MFMA/wave, half stage VALU
//      (2) rope table precomputed once in k_prep (no per-block sincosf/powf)
//      (3) k_zout: 512-thr blocks, 16 rows/wave, grid 512 = all blocks resident (2/CU)
// B=8 T=8192 DM=128 H=8 Dh=16.

typedef __attribute__((ext_vector_type(8))) short short8;   // 8 bf16 (MFMA A/B frag)
typedef __attribute__((ext_vector_type(4))) float floatx4;  // MFMA C/D frag

#define DEV __device__ __forceinline__
#define MFMA __builtin_amdgcn_mfma_f32_16x16x32_bf16

DEV unsigned short bfh(float f) {
  unsigned int x = __float_as_uint(f);
  x += 0x7fffu + ((x >> 16) & 1u);     // RNE
  return (unsigned short)(x >> 16);
}
DEV float bfdec(unsigned short u) { return __uint_as_float(((unsigned int)u) << 16); }
DEV void splitf(float f, unsigned short& h, unsigned short& l) {
  h = bfh(f);
  l = bfh(f - bfdec(h));
}

// Register transpose (verified R5-R8): C-layout tile val(n=lane16, m=mt*16+quad*4+r),
// rows m0/m1 -> split frag F[lane16][k=quad*8+j] over the 32-wide m-window.
DEV void xpose_frag(floatx4 m0, floatx4 m1, int lane16, int quad,
                    short8& hi, short8& lo) {
  union { short8 s; unsigned short u[8]; } H, L;
#pragma unroll
  for (int j = 0; j < 8; ++j) {
    int srcLane = lane16 + (((quad & 1) * 2 + (j >> 2)) << 4);
    float vA = __shfl(m0[j & 3], srcLane, 64);
    float vB = __shfl(m1[j & 3], srcLane, 64);
    float v = (quad < 2) ? vA : vB;
    splitf(v, H.u[j], L.u[j]);
  }
  hi = H.s; lo = L.s;
}

// async 16B global->LDS (per-lane gsrc; LDS dest = wave-uniform base + lane*16)
DEV void async16(const void* g, void* l) {
  __builtin_amdgcn_global_load_lds(
      (const __attribute__((address_space(1))) unsigned int*)g,
      (__attribute__((address_space(3))) unsigned int*)l, 16, 0, 0);
}

// ---------------- k_prep: W split-transpose + rope table + zero ctx/ksum ----------------
__global__ void k_prep(const float* __restrict__ Wq, const float* __restrict__ Wk,
                       const float* __restrict__ Wv,
                       unsigned short* __restrict__ WTh, unsigned short* __restrict__ WTl,
                       float* __restrict__ ctxz, float2* __restrict__ ropeT) {
  int gid = blockIdx.x * 256 + threadIdx.x;
  if (gid < 6144) {               // 3 mats x 128 n x 16 k-groups of 8
    int mat = gid >> 11, r = gid & 2047, n = r >> 4, k0 = (r & 15) * 8;
    const float* W = (mat == 0) ? Wq : (mat == 1) ? Wk : Wv;
    union { uint4 q; unsigned short u[8]; } oh, ol;
#pragma unroll
    for (int i = 0; i < 8; ++i) splitf(W[(size_t)(k0 + i) * 128 + n], oh.u[i], ol.u[i]);
    *(uint4*)&WTh[mat * 16384 + n * 128 + k0] = oh.q;
    *(uint4*)&WTl[mat * 16384 + n * 128 + k0] = ol.q;
  } else if (gid < 6144 + 17408) {
    ctxz[gid - 6144] = 0.0f;      // ctx (16384) + ksum (1024)
  } else if (gid < 6144 + 17408 + 65536) {
    int r = gid - 23552;          // (t,j): t = r>>3, j = r&7
    int t = r >> 3, j = r & 7;
    float invf = 1.0f / powf(10000.0f, (float)j * 0.125f);
    float s, c;
    sincosf((float)t * invf, &s, &c);
    ropeT[r] = make_float2(c, s);
  }
}

// ---------------- kernel 1: qkv GEMM + rope/elu + q'/ksum/ctx. 512 thr, wave=1 head ----------------
__global__ __launch_bounds__(512) void k_qkv(
    const float* __restrict__ x, const float2* __restrict__ ropeT,
    const unsigned short* __restrict__ WTh, const unsigned short* __restrict__ WTl,
    const float* __restrict__ bq, const float* __restrict__ bk, const float* __restrict__ bv,
    float* __restrict__ ctx, float* __restrict__ ksum,
    unsigned short* __restrict__ qws) {
  __shared__ unsigned short xh[64 * 136];        // x tile bf16-hi [row][k], pad 8 (17.4 KB)
  __shared__ float rc[64][9], rs[64][9];
  const int tid = threadIdx.x;
  const int row0 = blockIdx.x * 64;
  const int b = row0 >> 13;
  const int t0 = row0 & 8191;

  {  // rope slice: 512 threads -> 64 rows x 8 j (table lookup, no sincos)
    int r = tid >> 3, j = tid & 7;
    float2 cs = ropeT[(t0 + r) * 8 + j];
    rc[r][j] = cs.x; rs[r][j] = cs.y;
  }
  {  // stage x as bf16-hi
    int r = tid >> 3, cg = (tid & 7) * 16;
    const float* xp = x + (size_t)(row0 + r) * 128 + cg;
    float4 a = *(const float4*)xp;
    float4 b4 = *(const float4*)(xp + 4);
    float4 c4 = *(const float4*)(xp + 8);
    float4 d4 = *(const float4*)(xp + 12);
    float v[16] = {a.x, a.y, a.z, a.w, b4.x, b4.y, b4.z, b4.w,
                   c4.x, c4.y, c4.z, c4.w, d4.x, d4.y, d4.z, d4.w};
    union { short8 s; unsigned short u[8]; } h0, h1;
#pragma unroll
    for (int i = 0; i < 8; ++i) { h0.u[i] = bfh(v[i]); h1.u[i] = bfh(v[8 + i]); }
    *(short8*)&xh[r * 136 + cg] = h0.s;
    *(short8*)&xh[r * 136 + cg + 8] = h1.s;
  }
  __syncthreads();                 // only barrier

  const int l = tid & 63, w = tid >> 6;       // wave w owns head w
  const int lane16 = l & 15, quad = l >> 4;

  floatx4 acc[3][4];               // [mat: q,k,v][mt]  = 48 AGPRs
#pragma unroll
  for (int i = 0; i < 3; ++i)
#pragma unroll
    for (int j = 0; j < 4; ++j) acc[i][j] = (floatx4){0.f, 0.f, 0.f, 0.f};

  size_t wbase[3];
#pragma unroll
  for (int mat = 0; mat < 3; ++mat)
    wbase[mat] = (size_t)mat * 16384 + (size_t)(w * 16 + lane16) * 128 + quad * 8;

  // double-buffered weight frags
  short8 wh[2][3], wl[2][3];
#pragma unroll
  for (int mat = 0; mat < 3; ++mat) {
    wh[0][mat] = *(const short8*)(WTh + wbase[mat]);
    wl[0][mat] = *(const short8*)(WTl + wbase[mat]);
  }

#pragma unroll
  for (int ks = 0; ks < 4; ++ks) {
    const int cur = ks & 1, nxt = cur ^ 1;
    if (ks < 3) {
#pragma unroll
      for (int mat = 0; mat < 3; ++mat) {
        wh[nxt][mat] = *(const short8*)(WTh + wbase[mat] + (ks + 1) * 32);
        wl[nxt][mat] = *(const short8*)(WTl + wbase[mat] + (ks + 1) * 32);
      }
    }
    short8 afh[4];
#pragma unroll
    for (int mt = 0; mt < 4; ++mt)
      afh[mt] = *(const short8*)&xh[(mt * 16 + lane16) * 136 + ks * 32 + quad * 8];
#pragma unroll
    for (int mat = 0; mat < 3; ++mat) {
#pragma unroll
      for (int mt = 0; mt < 4; ++mt) {
        acc[mat][mt] = MFMA(afh[mt], wh[cur][mat], acc[mat][mt], 0, 0, 0);
        acc[mat][mt] = MFMA(afh[mt], wl[cur][mat], acc[mat][mt], 0, 0, 0);
      }
    }
  }

  // bias (lane16 = col within head)
  {
    int col = w * 16 + lane16;
    float bias[3] = {bq[col], bk[col], bv[col]};
#pragma unroll
    for (int mat = 0; mat < 3; ++mat)
#pragma unroll
      for (int mt = 0; mt < 4; ++mt)
#pragma unroll
        for (int r = 0; r < 4; ++r) acc[mat][mt][r] += bias[mat];
  }

  // rope + elu+1 on q (mat 0) and k (mat 1). lane16 = d; t = mt*16 + quad*4 + r.
  {
    const int d = lane16, j = d & 7;
#pragma unroll
    for (int mt = 0; mt < 4; ++mt) {
      float cc[4], ss[4];
#pragma unroll
      for (int r = 0; r < 4; ++r) {
        int tl = mt * 16 + quad * 4 + r;
        cc[r] = rc[tl][j]; ss[r] = rs[tl][j];
      }
#pragma unroll
      for (int mat = 0; mat < 2; ++mat) {
#pragma unroll
        for (int r = 0; r < 4; ++r) {
          float v = acc[mat][mt][r];
          float p = __shfl_xor(v, 8);          // pair (d, d+8)
          float nv = (d < 8) ? (v * cc[r] - p * ss[r]) : (p * ss[r] + v * cc[r]);
          acc[mat][mt][r] = (nv > 0.f) ? (nv + 1.f) : __expf(nv);
        }
      }
    }
  }

  // ksum[h=w][d] from k
  {
    float s = 0.f;
#pragma unroll
    for (int mt = 0; mt < 4; ++mt)
#pragma unroll
      for (int r = 0; r < 4; ++r) s += acc[1][mt][r];
    s += __shfl_xor(s, 16);
    s += __shfl_xor(s, 32);
    if (l < 16) atomicAdd(&ksum[(b * 8 + w) * 16 + lane16], s);
  }

  // q' -> ws bf16 [t][128]
#pragma unroll
  for (int mt = 0; mt < 4; ++mt)
#pragma unroll
    for (int r = 0; r < 4; ++r)
      qws[(size_t)(row0 + mt * 16 + quad * 4 + r) * 128 + w * 16 + lane16] =
          bfh(acc[0][mt][r]);

  // ctx[h=w] += K^T V via register transposes (2 t-windows of 32), full split
  {
    floatx4 c = (floatx4){0.f, 0.f, 0.f, 0.f};
#pragma unroll
    for (int ks2 = 0; ks2 < 2; ++ks2) {
      short8 kh, kl, vh, vl;
      xpose_frag(acc[1][ks2 * 2], acc[1][ks2 * 2 + 1], lane16, quad, kh, kl);
      xpose_frag(acc[2][ks2 * 2], acc[2][ks2 * 2 + 1], lane16, quad, vh, vl);
      c = MFMA(kh, vh, c, 0, 0, 0);
      c = MFMA(kl, vh, c, 0, 0, 0);
      c = MFMA(kh, vl, c, 0, 0, 0);
    }
#pragma unroll
    for (int r = 0; r < 4; ++r)
      atomicAdd(&ctx[((size_t)(b * 8 + w) * 16 + quad * 4 + r) * 16 + lane16], c[r]);
  }
}

// ---------------- k_mprep: M = C_h @ Wo_h (fp32) -> frag-major permuted split-bf16 ----------------
__global__ void k_mprep(const float* __restrict__ Wo, const float* __restrict__ ctx,
                        unsigned short* __restrict__ MTh, unsigned short* __restrict__ MTl) {
  int gid = blockIdx.x * 256 + threadIdx.x;   // 64 blocks: 8 b x 128 oc x 16 qc-groups
  int b = gid >> 11, r = gid & 2047, oc = r >> 4, qcg = r & 15;
  int h = qcg >> 1, d0 = (qcg & 1) * 8;
  const float* C = ctx + (size_t)(b * 8 + h) * 256;   // [d][e]
  float m[8] = {0.f, 0.f, 0.f, 0.f, 0.f, 0.f, 0.f, 0.f};
#pragma unroll 4
  for (int e = 0; e < 16; ++e) {
    float wv = Wo[(size_t)(h * 16 + e) * 128 + oc];
#pragma unroll
    for (int i = 0; i < 8; ++i) m[i] += C[(d0 + i) * 16 + e] * wv;
  }
  union { uint4 q; unsigned short u[8]; } oh, ol;
#pragma unroll
  for (int i = 0; i < 8; ++i) splitf(m[i], oh.u[i], ol.u[i]);
  // permuted group index: nt=oc>>4, ks=qcg>>2, l = (qcg&3)*16 + (oc&15)
  int grp = (((oc >> 4) * 4 + (qcg >> 2)) * 64) + (qcg & 3) * 16 + (oc & 15);
  *(uint4*)&MTh[(size_t)b * 16384 + grp * 8] = oh.q;
  *(uint4*)&MTl[(size_t)b * 16384 + grp * 8] = ol.q;
}

// ---------------- kernel 2: out = (z .* q') @ M + bo. 512 thr, 16 rows/wave ----------------
__global__ __launch_bounds__(512) void k_zout(
    const unsigned short* __restrict__ qws,
    const unsigned short* __restrict__ MTh, const unsigned short* __restrict__ MTl,
    const float* __restrict__ bo, const float* __restrict__ ksum,
    float* __restrict__ out) {
  __shared__ __align__(16) unsigned short mh[16384], ml[16384];  // 64 KB, frag-major
  __shared__ float ksumS[128], boS[128];
  const int tid = threadIdx.x;
  const int row0 = blockIdx.x * 128;
  const int b = row0 >> 13;
  const int l = tid & 63, w = tid >> 6;
  const int lane16 = l & 15, quad = l >> 4;

  {  // async-stage M (64 KB): wave w copies chunks (i*8+w)*1KB
    const char* gh = (const char*)(MTh + (size_t)b * 16384);
    const char* gl = (const char*)(MTl + (size_t)b * 16384);
#pragma unroll
    for (int i = 0; i < 4; ++i) {
      int off = (i * 8 + w) * 1024 + l * 16;
      async16(gh + off, (char*)mh + off);
      async16(gl + off, (char*)ml + off);
    }
  }
  if (tid < 128) ksumS[tid] = ksum[b * 128 + tid];
  else if (tid < 256) boS[tid - 128] = bo[tid - 128];
  __syncthreads();                 // drains async staging too

  // A-frags: q' direct from ws (already frag-layout), z in-reg, scale+split
  const int trow = row0 + w * 16 + lane16;           // lane16 = t
  short8 ah[4], al[4];
#pragma unroll
  for (int ks = 0; ks < 4; ++ks) {
    union { short8 s8; unsigned short u[8]; } qq;
    qq.s8 = *(const short8*)&qws[(size_t)trow * 128 + ks * 32 + quad * 8];
    int kb = ks * 32 + quad * 8;
    float s = 0.f;
#pragma unroll
    for (int j = 0; j < 8; ++j) s += bfdec(qq.u[j]) * ksumS[kb + j];
    s += __shfl_xor(s, 16);        // combine the two 8-halves of the head
    float z = 1.0f / (s + 1e-6f);
    union { short8 s8; unsigned short u[8]; } H, L;
#pragma unroll
    for (int j = 0; j < 8; ++j) splitf(bfdec(qq.u[j]) * z, H.u[j], L.u[j]);
    ah[ks] = H.s8;
    al[ks] = L.s8;
  }

  floatx4 oacc[8];
#pragma unroll
  for (int j = 0; j < 8; ++j) oacc[j] = (floatx4){0.f, 0.f, 0.f, 0.f};

#pragma unroll
  for (int nt = 0; nt < 8; ++nt) {
#pragma unroll
    for (int ks = 0; ks < 4; ++ks) {
      int moff = ((nt * 4 + ks) * 64 + l) * 8;        // frag-major: lane-contiguous 16B
      short8 wbh = *(const short8*)&mh[moff];
      short8 wbl = *(const short8*)&ml[moff];
      oacc[nt] = MFMA(ah[ks], wbh, oacc[nt], 0, 0, 0);
      oacc[nt] = MFMA(al[ks], wbh, oacc[nt], 0, 0, 0);
      oacc[nt] = MFMA(ah[ks], wbl, oacc[nt], 0, 0, 0);
    }
  }

#pragma unroll
  for (int nt = 0; nt < 8; ++nt) {
    int oc = nt * 16 + lane16;
    float bb = boS[oc];
#pragma unroll
    for (int r = 0; r < 4; ++r) {
      int t = row0 + w * 16 + quad * 4 + r;
      out[(size_t)t * 128 + oc] = oacc[nt][r] + bb;
    }
  }
}

extern "C" void kernel_launch(void* const* d_in, const int* in_sizes, int n_in,
                              void* d_out, int out_size, void* d_ws, size_t ws_size,
                              hipStream_t stream) {
  const float* x  = (const float*)d_in[0];
  const float* Wq = (const float*)d_in[1];
  const float* bq = (const float*)d_in[2];
  const float* Wk = (const float*)d_in[3];
  const float* bk = (const float*)d_in[4];
  const float* Wv = (const float*)d_in[5];
  const float* bv = (const float*)d_in[6];
  const float* Wo = (const float*)d_in[7];
  const float* bo = (const float*)d_in[8];
  float* out = (float*)d_out;

  // ws: qws 16.78MB | WTh 96KB | WTl 96KB | ctx 64KB | ksum 4KB | MTh 256KB | MTl 256KB | ropeT 512KB
  unsigned short* qws = (unsigned short*)d_ws;           // 65536*128 shorts
  unsigned short* WTh = qws + 8388608;                   // 3 x 16384
  unsigned short* WTl = WTh + 49152;
  float* ctx  = (float*)(WTl + 49152);                   // 16384 f
  float* ksum = ctx + 16384;                             // 1024 f
  unsigned short* MTh = (unsigned short*)(ksum + 1024);  // 8 x 16384
  unsigned short* MTl = MTh + 131072;
  float2* ropeT = (float2*)(MTl + 131072);               // 65536 float2

  k_prep<<<348, 256, 0, stream>>>(Wq, Wk, Wv, WTh, WTl, ctx, ropeT);
  k_qkv<<<1024, 512, 0, stream>>>(x, ropeT, WTh, WTl, bq, bk, bv, ctx, ksum, qws);
  k_mprep<<<64, 256, 0, stream>>>(Wo, ctx, MTh, MTl);
  k_zout<<<512, 512, 0, stream>>>(qws, MTh, MTl, bo, ksum, out);
}